// Round 3
// baseline (92.757 us; speedup 1.0000x reference)
//
#include <hip/hip_runtime.h>
#include <hip/hip_bf16.h>

#define B_   16
#define T_   8192
#define H_   256
#define C_   11
#define KCH  256            // chunks per batch
#define LCH  32             // steps per chunk (T_/KCH)
#define NC   (B_*KCH)       // total chunks

// round-to-nearest-even fp32 -> bf16 (returns bits in low 16)
__device__ __forceinline__ unsigned bf16rne(float x) {
    unsigned b = __float_as_uint(x);
    return (b + 0x7fffu + ((b >> 16) & 1u)) >> 16;
}

// numerator contribution of one (b,t) position, using em row in registers
__device__ __forceinline__ float numContrib(const float* acc, int t, int len,
    const int* __restrict__ lab, const float* __restrict__ trans,
    const float* __restrict__ startt, const float* __restrict__ endt)
{
    int tg = lab[t]; if (tg < 0) tg = 0;
    float emt = acc[0];
#pragma unroll
    for (int c = 1; c < C_; c++) emt = (tg == c) ? acc[c] : emt;
    float r = 0.f;
    if (t == 0) {
        r += startt[tg] + emt;
    } else if (t < len) {
        int tp = lab[t - 1]; if (tp < 0) tp = 0;
        r += trans[tp * C_ + tg] + emt;
    }
    if (t == len - 1) r += endt[tg];
    return r;
}

// ---------------------------------------------------------------------------
// K1: encoder + emissions + fused numerator. Weights read via wave-uniform
// global loads (compiler scalarizes to s_load -> SGPRs; zero LDS traffic).
// One row per thread; 512 blocks -> 2 waves/SIMD. exp(em) stored bf16,
// 16 shorts/row (32B, aligned).
// ---------------------------------------------------------------------------
__global__ __launch_bounds__(256) void k_em(
    const float* __restrict__ seq, const float* __restrict__ Wenc,
    const float* __restrict__ benc, const float* __restrict__ Wemit,
    const float* __restrict__ bemit, const float* __restrict__ trans,
    const float* __restrict__ startt, const float* __restrict__ endt,
    const int* __restrict__ lengths, const int* __restrict__ labels,
    unsigned short* __restrict__ expem, float* __restrict__ numpart)
{
    __shared__ float red[4];
    int tid = threadIdx.x;
    int r0 = blockIdx.x * 256 + tid;
    float4 x = *(const float4*)(seq + (size_t)r0 * 4);
    float acc[C_];
#pragma unroll
    for (int c = 0; c < C_; c++) acc[c] = bemit[c];

#pragma unroll 4
    for (int h = 0; h < H_; h++) {
        float hv = fmaf(x.x, Wenc[h],
                   fmaf(x.y, Wenc[H_ + h],
                   fmaf(x.z, Wenc[2 * H_ + h],
                   fmaf(x.w, Wenc[3 * H_ + h], benc[h]))));
        hv = fmaxf(hv, 0.f);
        const float* wr = Wemit + h * C_;
#pragma unroll
        for (int c = 0; c < C_; c++) acc[c] = fmaf(hv, wr[c], acc[c]);
    }

    // fused numerator (em in exact fp32 log space)
    int b = r0 >> 13;                 // 8192 rows per batch
    int t = r0 & (T_ - 1);
    int len = lengths[b];
    const int* lab = labels + (size_t)b * T_;
    float nacc = numContrib(acc, t, len, lab, trans, startt, endt);

    // exp + bf16 pack + store (32B/row)
    float e[11];
#pragma unroll
    for (int c = 0; c < C_; c++) e[c] = __expf(acc[c]);
    unsigned p01 = bf16rne(e[0]) | (bf16rne(e[1]) << 16);
    unsigned p23 = bf16rne(e[2]) | (bf16rne(e[3]) << 16);
    unsigned p45 = bf16rne(e[4]) | (bf16rne(e[5]) << 16);
    unsigned p67 = bf16rne(e[6]) | (bf16rne(e[7]) << 16);
    unsigned p89 = bf16rne(e[8]) | (bf16rne(e[9]) << 16);
    unsigned pAB = bf16rne(e[10]);
    unsigned short* orow = expem + (size_t)r0 * 16;
    *(uint4*)orow = make_uint4(p01, p23, p45, p67);
    *(uint2*)(orow + 8) = make_uint2(p89, pAB);

    // block reduce numerator
#pragma unroll
    for (int off = 32; off > 0; off >>= 1) nacc += __shfl_down(nacc, off);
    if ((tid & 63) == 0) red[tid >> 6] = nacc;
    __syncthreads();
    if (tid == 0) numpart[blockIdx.x] = red[0] + red[1] + red[2] + red[3];
}

// ---------------------------------------------------------------------------
// bf16 emission row load/unpack helpers
// ---------------------------------------------------------------------------
__device__ __forceinline__ void loadRow(const unsigned short* __restrict__ p,
                                        uint4& qa, uint2& qb) {
    qa = *(const uint4*)p;
    qb = *(const uint2*)(p + 8);
}
__device__ __forceinline__ void unpackRow(uint4 qa, uint2 qb, float* emv) {
    emv[0]  = __uint_as_float(qa.x << 16);
    emv[1]  = __uint_as_float(qa.x & 0xffff0000u);
    emv[2]  = __uint_as_float(qa.y << 16);
    emv[3]  = __uint_as_float(qa.y & 0xffff0000u);
    emv[4]  = __uint_as_float(qa.z << 16);
    emv[5]  = __uint_as_float(qa.z & 0xffff0000u);
    emv[6]  = __uint_as_float(qa.w << 16);
    emv[7]  = __uint_as_float(qa.w & 0xffff0000u);
    emv[8]  = __uint_as_float(qb.x << 16);
    emv[9]  = __uint_as_float(qb.x & 0xffff0000u);
    emv[10] = __uint_as_float(qb.y << 16);
}

// ---------------------------------------------------------------------------
// K2: per-chunk transfer matrices, probability domain, per-row rescale.
// Fast path for fully-active chunks (no mask VALU), identity for fully-dead,
// masked path only for the one boundary chunk per batch.
// ---------------------------------------------------------------------------
__global__ __launch_bounds__(256) void k_chunks(
    const float* __restrict__ trans, const int* __restrict__ lengths,
    const unsigned short* __restrict__ expem, float* __restrict__ G)
{
    int tid = threadIdx.x;
    int lane = tid & 63, w = tid >> 6;
    int ciw = lane / C_;            // 5 chunks per wave (55/64 lanes)
    int i = lane - ciw * C_;
    int cid = blockIdx.x * 20 + w * 5 + ciw;
    if (ciw >= 5 || cid >= NC) return;

    int b = cid >> 8;
    int k = cid & (KCH - 1);
    int t0 = 1 + k * LCH;
    int len = lengths[b];
    float* o = G + (size_t)cid * 132 + i * 12;

    if (t0 >= len) {                 // fully inactive -> identity
#pragma unroll
        for (int j = 0; j < C_; j++) o[j] = (j == i) ? 1.f : 0.f;
        o[11] = 0.f;
        return;
    }

    float eT[121];
#pragma unroll
    for (int z = 0; z < 121; z++) eT[z] = __expf(trans[z]);

    float g[C_];
#pragma unroll
    for (int j = 0; j < C_; j++) g[j] = (j == i) ? 1.f : 0.f;
    float ls = 0.f;

    const unsigned short* emb = expem + (size_t)b * T_ * 16;
    bool full = (t0 + LCH <= len);

    if (full) {
        uint4 ca; uint2 cb;
        loadRow(emb + (size_t)t0 * 16, ca, cb);
#pragma unroll 1
        for (int su = 0; su < LCH / 4; su++) {
#pragma unroll
            for (int ss = 0; ss < 4; ss++) {
                int t = t0 + su * 4 + ss;
                int tn = t + 1; tn = (tn < T_) ? tn : (T_ - 1);
                uint4 na; uint2 nb;
                loadRow(emb + (size_t)tn * 16, na, nb);   // prefetch next
                float emv[C_];
                unpackRow(ca, cb, emv);
                float nxt[C_];
#pragma unroll
                for (int j = 0; j < C_; j++) nxt[j] = g[0] * eT[j];
#pragma unroll
                for (int kk = 1; kk < C_; kk++)
#pragma unroll
                    for (int j = 0; j < C_; j++)
                        nxt[j] = fmaf(g[kk], eT[kk * C_ + j], nxt[j]);
#pragma unroll
                for (int j = 0; j < C_; j++) g[j] = nxt[j] * emv[j];
                ca = na; cb = nb;
            }
            float s = 0.f;
#pragma unroll
            for (int j = 0; j < C_; j++) s += g[j];
            float r = 1.f / s;
#pragma unroll
            for (int j = 0; j < C_; j++) g[j] *= r;
            ls += __logf(s);
        }
    } else {                          // boundary chunk (rare)
#pragma unroll 1
        for (int su = 0; su < LCH / 4; su++) {
#pragma unroll
            for (int ss = 0; ss < 4; ss++) {
                int t = t0 + su * 4 + ss;
                int tc = (t < T_) ? t : (T_ - 1);
                uint4 ca; uint2 cb;
                loadRow(emb + (size_t)tc * 16, ca, cb);
                float emv[C_];
                unpackRow(ca, cb, emv);
                float nxt[C_];
#pragma unroll
                for (int j = 0; j < C_; j++) nxt[j] = g[0] * eT[j];
#pragma unroll
                for (int kk = 1; kk < C_; kk++)
#pragma unroll
                    for (int j = 0; j < C_; j++)
                        nxt[j] = fmaf(g[kk], eT[kk * C_ + j], nxt[j]);
                bool act = (t < len);
#pragma unroll
                for (int j = 0; j < C_; j++) g[j] = act ? nxt[j] * emv[j] : g[j];
            }
            float s = 0.f;
#pragma unroll
            for (int j = 0; j < C_; j++) s += g[j];
            float r = 1.f / s;
#pragma unroll
            for (int j = 0; j < C_; j++) g[j] *= r;
            ls += __logf(s);
        }
    }

#pragma unroll
    for (int j = 0; j < C_; j++) o[j] = g[j];
    o[11] = ls;
}

// ---------------------------------------------------------------------------
// K3: per-batch tree combine entirely in LDS (135 KiB), 512 threads, then den.
// In-place: level writes go to slots ≡0 (mod 2*stride), reads of B-slots are
// ≡stride (mod 2*stride) -> disjoint; own-A-row read/write is same task.
// ---------------------------------------------------------------------------
__global__ __launch_bounds__(512, 1) void k_comb(
    const float* __restrict__ startt, const float* __restrict__ endt,
    const unsigned short* __restrict__ expem, const float* __restrict__ G0,
    float* __restrict__ dens)
{
    __shared__ float M[KCH * 132];     // 135168 bytes
    int b = blockIdx.x, tid = threadIdx.x;
    const float4* src = (const float4*)(G0 + (size_t)b * KCH * 132);
    float4* dst = (float4*)M;
#pragma unroll 2
    for (int idx = tid; idx < KCH * 132 / 4; idx += 512) dst[idx] = src[idx];
    __syncthreads();

    for (int stride = 1; stride < KCH; stride <<= 1) {
        int npair = KCH / (2 * stride);
        for (int task = tid; task < npair * C_; task += 512) {
            int p = task / C_, i = task - p * C_;
            float* A  = M + (size_t)(2 * stride * p) * 132;
            float* Bm = M + (size_t)(2 * stride * p + stride) * 132;
            float a[C_];
#pragma unroll
            for (int kk = 0; kk < C_; kk++) a[kk] = A[i * 12 + kk];
            float als = A[i * 12 + 11];
            float m = Bm[11];
#pragma unroll
            for (int kk = 1; kk < C_; kk++) m = fmaxf(m, Bm[kk * 12 + 11]);
            float wv[C_];
#pragma unroll
            for (int kk = 0; kk < C_; kk++)
                wv[kk] = a[kk] * __expf(Bm[kk * 12 + 11] - m);
            float out[C_];
#pragma unroll
            for (int j = 0; j < C_; j++) out[j] = wv[0] * Bm[j];
#pragma unroll
            for (int kk = 1; kk < C_; kk++)
#pragma unroll
                for (int j = 0; j < C_; j++)
                    out[j] = fmaf(wv[kk], Bm[kk * 12 + j], out[j]);
            float s = 0.f;
#pragma unroll
            for (int j = 0; j < C_; j++) s += out[j];
            float rr = 1.f / s;
#pragma unroll
            for (int j = 0; j < C_; j++) A[i * 12 + j] = out[j] * rr;
            A[i * 12 + 11] = als + m + __logf(s);
        }
        __syncthreads();
    }

    if (tid == 0) {
        const float* Cm = M;                       // total matrix
        const unsigned short* em0 = expem + (size_t)b * T_ * 16;
        float av[C_];
        float mm = -1e30f;
#pragma unroll
        for (int i2 = 0; i2 < C_; i2++) {
            float e0 = __uint_as_float((unsigned)em0[i2] << 16);
            av[i2] = startt[i2] + __logf(e0) + Cm[i2 * 12 + 11];
            mm = fmaxf(mm, av[i2]);
        }
        float S[C_];
#pragma unroll
        for (int j = 0; j < C_; j++) S[j] = 0.f;
#pragma unroll
        for (int i2 = 0; i2 < C_; i2++) {
            float e = __expf(av[i2] - mm);
#pragma unroll
            for (int j = 0; j < C_; j++) S[j] = fmaf(e, Cm[i2 * 12 + j], S[j]);
        }
        float tot = 0.f;
#pragma unroll
        for (int j = 0; j < C_; j++) tot += S[j] * __expf(endt[j]);
        dens[b] = __logf(tot) + mm;
    }
}

// ---------------------------------------------------------------------------
// K4: final scalar: -(sum(numpart) - sum(dens)) / B
// ---------------------------------------------------------------------------
__global__ __launch_bounds__(512) void k_final(
    const float* __restrict__ numpart, const float* __restrict__ dens,
    float* __restrict__ out)
{
    __shared__ float red[8];
    int tid = threadIdx.x;
    float v = numpart[tid];
    if (tid < B_) v -= dens[tid];
#pragma unroll
    for (int off = 32; off > 0; off >>= 1) v += __shfl_down(v, off);
    if ((tid & 63) == 0) red[tid >> 6] = v;
    __syncthreads();
    if (tid == 0) {
        float s = 0.f;
#pragma unroll
        for (int q = 0; q < 8; q++) s += red[q];
        out[0] = -s / (float)B_;
    }
}

extern "C" void kernel_launch(void* const* d_in, const int* in_sizes, int n_in,
                              void* d_out, int out_size, void* d_ws, size_t ws_size,
                              hipStream_t stream) {
    const float* seq    = (const float*)d_in[0];
    const float* Wenc   = (const float*)d_in[1];
    const float* benc   = (const float*)d_in[2];
    const float* Wemit  = (const float*)d_in[3];
    const float* bemit  = (const float*)d_in[4];
    const float* startt = (const float*)d_in[5];
    const float* trans  = (const float*)d_in[6];
    const float* endt   = (const float*)d_in[7];
    const int*   lengths= (const int*)d_in[8];
    const int*   labels = (const int*)d_in[9];

    unsigned short* expem = (unsigned short*)d_ws;             // B*T*16 bf16
    float* G0      = (float*)(expem + (size_t)B_ * T_ * 16);   // NC*132 f32
    float* numpart = G0 + (size_t)NC * 132;                    // 512
    float* dens    = numpart + 512;                            // B
    float* out     = (float*)d_out;

    k_em<<<512, 256, 0, stream>>>(seq, Wenc, benc, Wemit, bemit, trans,
                                  startt, endt, lengths, labels, expem, numpart);
    k_chunks<<<(NC + 19) / 20, 256, 0, stream>>>(trans, lengths, expem, G0);
    k_comb<<<B_, 512, 0, stream>>>(startt, endt, expem, G0, dens);
    k_final<<<1, 512, 0, stream>>>(numpart, dens, out);
}

// Round 4
// 84.696 us; speedup vs baseline: 1.0952x; 1.0952x over previous
//
#include <hip/hip_runtime.h>
#include <hip/hip_bf16.h>

#define B_   16
#define T_   8192
#define H_   256
#define C_   11
#define KCH  256            // chunks per batch
#define LCH  32             // steps per chunk (T_/KCH)
#define NC   (B_*KCH)       // total chunks

typedef __attribute__((ext_vector_type(8))) short short8;
typedef __attribute__((ext_vector_type(4))) float f32x4;

// round-to-nearest-even fp32 -> bf16 (bits in low 16)
__device__ __forceinline__ unsigned bf16rne(float x) {
    unsigned b = __float_as_uint(x);
    return (b + 0x7fffu + ((b >> 16) & 1u)) >> 16;
}

// ---------------------------------------------------------------------------
// K0: prep — pack enc weights per (kb,g) in fragment order, Wemit^T A-frags,
// and exp(trans). Fragment k-map: k = 4*g + (e&3) + 16*(e>>2)  (consistent
// between A and B by construction; C/D layout is the HW-verified one).
// ---------------------------------------------------------------------------
__global__ __launch_bounds__(256) void k_prep(
    const float* __restrict__ Wenc, const float* __restrict__ benc,
    const float* __restrict__ Wemit, const float* __restrict__ trans,
    float* __restrict__ wpack, unsigned short* __restrict__ Afrag,
    float* __restrict__ eT)
{
    int tid = threadIdx.x;
    // wpack[kbg][48]: 40 used = 8 h-slots x (w0..w3, benc)
    for (int idx = tid; idx < 32 * 40; idx += 256) {
        int kbg = idx / 40, r = idx - kbg * 40;
        int s = r / 5, q = r - s * 5;
        int kb = kbg >> 2, g = kbg & 3;
        int h = 32 * kb + 4 * g + (s & 3) + 16 * (s >> 2);
        wpack[kbg * 48 + r] = (q < 4) ? Wenc[q * H_ + h] : benc[h];
    }
    // Afrag[kb][lane][e] = bf16(Wemit[k][i]), i = lane&15 (0 pad for i>=11)
    for (int idx = tid; idx < 8 * 64 * 8; idx += 256) {
        int e = idx & 7, lane = (idx >> 3) & 63, kb = idx >> 9;
        int g = lane >> 4, i = lane & 15;
        int h = 32 * kb + 4 * g + (e & 3) + 16 * (e >> 2);
        float v = (i < C_) ? Wemit[h * C_ + i] : 0.f;
        Afrag[idx] = (unsigned short)bf16rne(v);
    }
    if (tid < 121) eT[tid] = __expf(trans[tid]);
}

// component j (compile-time) of the packed weight block
#define WF(j) (((j) & 3) == 0 ? Wq[(j) >> 2].x : ((j) & 3) == 1 ? Wq[(j) >> 2].y \
             : ((j) & 3) == 2 ? Wq[(j) >> 2].z : Wq[(j) >> 2].w)

// ---------------------------------------------------------------------------
// K1: MFMA encoder+emissions+numerator. Wave = 4 tiles x 16 rows.
// B-frag (hidden) computed in-register: lane covers row t=lane&15 at its
// fragment's h-indices. A-frag = Wemit^T. em^T tile lands in C with
// row=c=4*(lane>>4)+reg, col=t=lane&15 (m89-verified layout).
// ---------------------------------------------------------------------------
__global__ __launch_bounds__(256) void k_em(
    const float* __restrict__ seq, const unsigned short* __restrict__ Afrag,
    const float* __restrict__ wpack, const float* __restrict__ bemit,
    const float* __restrict__ trans, const float* __restrict__ startt,
    const float* __restrict__ endt, const int* __restrict__ lengths,
    const int* __restrict__ labels,
    unsigned short* __restrict__ expem, float* __restrict__ numpart)
{
    __shared__ float red[4];
    int tid = threadIdx.x;
    int wid = tid >> 6, lane = tid & 63;
    int g = lane >> 4, li = lane & 15;

    int b = blockIdx.x >> 5;                          // 32 blocks per batch
    int tb0 = (blockIdx.x & 31) * 256 + wid * 64;     // within-batch wave base
    size_t grow0 = (size_t)b * T_ + tb0;

    float4 xs[4];
#pragma unroll
    for (int tt = 0; tt < 4; tt++)
        xs[tt] = *(const float4*)(seq + (grow0 + tt * 16 + li) * 4);

    f32x4 acc[4];
#pragma unroll
    for (int tt = 0; tt < 4; tt++) acc[tt] = (f32x4){0.f, 0.f, 0.f, 0.f};

#pragma unroll 1
    for (int kb = 0; kb < 8; kb++) {
        const float4* wp4 = (const float4*)(wpack + ((kb << 2) | g) * 48);
        float4 Wq[10];
#pragma unroll
        for (int i = 0; i < 10; i++) Wq[i] = wp4[i];
        short8 afk = *(const short8*)(Afrag + (kb << 9) + (lane << 3));

#pragma unroll
        for (int tt = 0; tt < 4; tt++) {
            float4 x = xs[tt];
            float hv[8];
#pragma unroll
            for (int e = 0; e < 8; e++) {
                float h = fmaf(x.x, WF(5 * e + 0),
                          fmaf(x.y, WF(5 * e + 1),
                          fmaf(x.z, WF(5 * e + 2),
                          fmaf(x.w, WF(5 * e + 3), WF(5 * e + 4)))));
                hv[e] = fmaxf(h, 0.f);
            }
            unsigned u0, u1, u2, u3;
            asm("v_cvt_pk_bf16_f32 %0, %1, %2" : "=v"(u0) : "v"(hv[0]), "v"(hv[1]));
            asm("v_cvt_pk_bf16_f32 %0, %1, %2" : "=v"(u1) : "v"(hv[2]), "v"(hv[3]));
            asm("v_cvt_pk_bf16_f32 %0, %1, %2" : "=v"(u2) : "v"(hv[4]), "v"(hv[5]));
            asm("v_cvt_pk_bf16_f32 %0, %1, %2" : "=v"(u3) : "v"(hv[6]), "v"(hv[7]));
            union { short8 s8; uint4 u4; } bfu;
            bfu.u4 = make_uint4(u0, u1, u2, u3);
            acc[tt] = __builtin_amdgcn_mfma_f32_16x16x32_bf16(afk, bfu.s8, acc[tt], 0, 0, 0);
        }
    }

    // epilogue: +bemit, numerator gather (fp32 em), exp, bf16 pack, store
    int len = lengths[b];
    const int* lab = labels + (size_t)b * T_;
    float bm[4];
#pragma unroll
    for (int r = 0; r < 4; r++) {
        int c = 4 * g + r;
        bm[r] = (c < C_) ? bemit[c] : 0.f;
    }

    float nacc = 0.f;
#pragma unroll
    for (int tt = 0; tt < 4; tt++) {
        float em0 = acc[tt].x + bm[0];
        float em1 = acc[tt].y + bm[1];
        float em2 = acc[tt].z + bm[2];
        float em3 = acc[tt].w + bm[3];

        int t = tb0 + tt * 16 + li;
        int tg = lab[t]; tg = tg < 0 ? 0 : tg;
        if (g == (tg >> 2) && t < len) {
            int r = tg & 3;
            float emtg = r == 0 ? em0 : r == 1 ? em1 : r == 2 ? em2 : em3;
            float contrib;
            if (t == 0) {
                contrib = startt[tg] + emtg;
            } else {
                int tp = lab[t - 1]; tp = tp < 0 ? 0 : tp;
                contrib = trans[tp * C_ + tg] + emtg;
            }
            if (t == len - 1) contrib += endt[tg];
            nacc += contrib;
        }

        if (g < 3) {
            float e0 = __expf(em0), e1 = __expf(em1);
            float e2 = __expf(em2), e3 = __expf(em3);
            unsigned u0, u1;
            asm("v_cvt_pk_bf16_f32 %0, %1, %2" : "=v"(u0) : "v"(e0), "v"(e1));
            asm("v_cvt_pk_bf16_f32 %0, %1, %2" : "=v"(u1) : "v"(e2), "v"(e3));
            *(uint2*)(expem + (grow0 + tt * 16 + li) * 16 + g * 4) = make_uint2(u0, u1);
        }
    }

#pragma unroll
    for (int off = 32; off > 0; off >>= 1) nacc += __shfl_down(nacc, off);
    if (lane == 0) red[wid] = nacc;
    __syncthreads();
    if (tid == 0) numpart[blockIdx.x] = red[0] + red[1] + red[2] + red[3];
}

// ---------------------------------------------------------------------------
// bf16 emission row load/unpack helpers
// ---------------------------------------------------------------------------
__device__ __forceinline__ void loadRow(const unsigned short* __restrict__ p,
                                        uint4& qa, uint2& qb) {
    qa = *(const uint4*)p;
    qb = *(const uint2*)(p + 8);
}
__device__ __forceinline__ void unpackRow(uint4 qa, uint2 qb, float* emv) {
    emv[0]  = __uint_as_float(qa.x << 16);
    emv[1]  = __uint_as_float(qa.x & 0xffff0000u);
    emv[2]  = __uint_as_float(qa.y << 16);
    emv[3]  = __uint_as_float(qa.y & 0xffff0000u);
    emv[4]  = __uint_as_float(qa.z << 16);
    emv[5]  = __uint_as_float(qa.z & 0xffff0000u);
    emv[6]  = __uint_as_float(qa.w << 16);
    emv[7]  = __uint_as_float(qa.w & 0xffff0000u);
    emv[8]  = __uint_as_float(qb.x << 16);
    emv[9]  = __uint_as_float(qb.x & 0xffff0000u);
    emv[10] = __uint_as_float(qb.y << 16);
}

// ---------------------------------------------------------------------------
// K2: per-chunk transfer matrices, probability domain, per-row rescale.
// exp(trans) preloaded from global (prep kernel) instead of 121 expf/lane.
// ---------------------------------------------------------------------------
__global__ __launch_bounds__(256) void k_chunks(
    const float* __restrict__ eTg, const int* __restrict__ lengths,
    const unsigned short* __restrict__ expem, float* __restrict__ G)
{
    int tid = threadIdx.x;
    int lane = tid & 63, w = tid >> 6;
    int ciw = lane / C_;            // 5 chunks per wave (55/64 lanes)
    int i = lane - ciw * C_;
    int cid = blockIdx.x * 20 + w * 5 + ciw;
    if (ciw >= 5 || cid >= NC) return;

    int b = cid >> 8;
    int k = cid & (KCH - 1);
    int t0 = 1 + k * LCH;
    int len = lengths[b];
    float* o = G + (size_t)cid * 132 + i * 12;

    if (t0 >= len) {                 // fully inactive -> identity
#pragma unroll
        for (int j = 0; j < C_; j++) o[j] = (j == i) ? 1.f : 0.f;
        o[11] = 0.f;
        return;
    }

    float eT[121];
#pragma unroll
    for (int z = 0; z < 121; z++) eT[z] = eTg[z];

    float g[C_];
#pragma unroll
    for (int j = 0; j < C_; j++) g[j] = (j == i) ? 1.f : 0.f;
    float ls = 0.f;

    const unsigned short* emb = expem + (size_t)b * T_ * 16;
    bool full = (t0 + LCH <= len);

    if (full) {
        uint4 ca; uint2 cb;
        loadRow(emb + (size_t)t0 * 16, ca, cb);
#pragma unroll 1
        for (int su = 0; su < LCH / 4; su++) {
#pragma unroll
            for (int ss = 0; ss < 4; ss++) {
                int t = t0 + su * 4 + ss;
                int tn = t + 1; tn = (tn < T_) ? tn : (T_ - 1);
                uint4 na; uint2 nb;
                loadRow(emb + (size_t)tn * 16, na, nb);   // prefetch next
                float emv[C_];
                unpackRow(ca, cb, emv);
                float nxt[C_];
#pragma unroll
                for (int j = 0; j < C_; j++) nxt[j] = g[0] * eT[j];
#pragma unroll
                for (int kk = 1; kk < C_; kk++)
#pragma unroll
                    for (int j = 0; j < C_; j++)
                        nxt[j] = fmaf(g[kk], eT[kk * C_ + j], nxt[j]);
#pragma unroll
                for (int j = 0; j < C_; j++) g[j] = nxt[j] * emv[j];
                ca = na; cb = nb;
            }
            float s = 0.f;
#pragma unroll
            for (int j = 0; j < C_; j++) s += g[j];
            float r = 1.f / s;
#pragma unroll
            for (int j = 0; j < C_; j++) g[j] *= r;
            ls += __logf(s);
        }
    } else {                          // boundary chunk (rare)
#pragma unroll 1
        for (int su = 0; su < LCH / 4; su++) {
#pragma unroll
            for (int ss = 0; ss < 4; ss++) {
                int t = t0 + su * 4 + ss;
                int tc = (t < T_) ? t : (T_ - 1);
                uint4 ca; uint2 cb;
                loadRow(emb + (size_t)tc * 16, ca, cb);
                float emv[C_];
                unpackRow(ca, cb, emv);
                float nxt[C_];
#pragma unroll
                for (int j = 0; j < C_; j++) nxt[j] = g[0] * eT[j];
#pragma unroll
                for (int kk = 1; kk < C_; kk++)
#pragma unroll
                    for (int j = 0; j < C_; j++)
                        nxt[j] = fmaf(g[kk], eT[kk * C_ + j], nxt[j]);
                bool act = (t < len);
#pragma unroll
                for (int j = 0; j < C_; j++) g[j] = act ? nxt[j] * emv[j] : g[j];
            }
            float s = 0.f;
#pragma unroll
            for (int j = 0; j < C_; j++) s += g[j];
            float r = 1.f / s;
#pragma unroll
            for (int j = 0; j < C_; j++) g[j] *= r;
            ls += __logf(s);
        }
    }

#pragma unroll
    for (int j = 0; j < C_; j++) o[j] = g[j];
    o[11] = ls;
}

// ---------------------------------------------------------------------------
// K3: per-batch tree combine entirely in LDS (135 KiB), 512 threads, then den.
// ---------------------------------------------------------------------------
__global__ __launch_bounds__(512, 1) void k_comb(
    const float* __restrict__ startt, const float* __restrict__ endt,
    const unsigned short* __restrict__ expem, const float* __restrict__ G0,
    float* __restrict__ dens)
{
    __shared__ float M[KCH * 132];     // 135168 bytes
    int b = blockIdx.x, tid = threadIdx.x;
    const float4* src = (const float4*)(G0 + (size_t)b * KCH * 132);
    float4* dst = (float4*)M;
#pragma unroll 2
    for (int idx = tid; idx < KCH * 132 / 4; idx += 512) dst[idx] = src[idx];
    __syncthreads();

    for (int stride = 1; stride < KCH; stride <<= 1) {
        int npair = KCH / (2 * stride);
        for (int task = tid; task < npair * C_; task += 512) {
            int p = task / C_, i = task - p * C_;
            float* A  = M + (size_t)(2 * stride * p) * 132;
            float* Bm = M + (size_t)(2 * stride * p + stride) * 132;
            float a[C_];
#pragma unroll
            for (int kk = 0; kk < C_; kk++) a[kk] = A[i * 12 + kk];
            float als = A[i * 12 + 11];
            float m = Bm[11];
#pragma unroll
            for (int kk = 1; kk < C_; kk++) m = fmaxf(m, Bm[kk * 12 + 11]);
            float wv[C_];
#pragma unroll
            for (int kk = 0; kk < C_; kk++)
                wv[kk] = a[kk] * __expf(Bm[kk * 12 + 11] - m);
            float out[C_];
#pragma unroll
            for (int j = 0; j < C_; j++) out[j] = wv[0] * Bm[j];
#pragma unroll
            for (int kk = 1; kk < C_; kk++)
#pragma unroll
                for (int j = 0; j < C_; j++)
                    out[j] = fmaf(wv[kk], Bm[kk * 12 + j], out[j]);
            float s = 0.f;
#pragma unroll
            for (int j = 0; j < C_; j++) s += out[j];
            float rr = 1.f / s;
#pragma unroll
            for (int j = 0; j < C_; j++) A[i * 12 + j] = out[j] * rr;
            A[i * 12 + 11] = als + m + __logf(s);
        }
        __syncthreads();
    }

    if (tid == 0) {
        const float* Cm = M;
        const unsigned short* em0 = expem + (size_t)b * T_ * 16;
        float av[C_];
        float mm = -1e30f;
#pragma unroll
        for (int i2 = 0; i2 < C_; i2++) {
            float e0 = __uint_as_float((unsigned)em0[i2] << 16);
            av[i2] = startt[i2] + __logf(e0) + Cm[i2 * 12 + 11];
            mm = fmaxf(mm, av[i2]);
        }
        float S[C_];
#pragma unroll
        for (int j = 0; j < C_; j++) S[j] = 0.f;
#pragma unroll
        for (int i2 = 0; i2 < C_; i2++) {
            float e = __expf(av[i2] - mm);
#pragma unroll
            for (int j = 0; j < C_; j++) S[j] = fmaf(e, Cm[i2 * 12 + j], S[j]);
        }
        float tot = 0.f;
#pragma unroll
        for (int j = 0; j < C_; j++) tot += S[j] * __expf(endt[j]);
        dens[b] = __logf(tot) + mm;
    }
}

// ---------------------------------------------------------------------------
// K4: final scalar: -(sum(numpart) - sum(dens)) / B
// ---------------------------------------------------------------------------
__global__ __launch_bounds__(512) void k_final(
    const float* __restrict__ numpart, const float* __restrict__ dens,
    float* __restrict__ out)
{
    __shared__ float red[8];
    int tid = threadIdx.x;
    float v = numpart[tid];
    if (tid < B_) v -= dens[tid];
#pragma unroll
    for (int off = 32; off > 0; off >>= 1) v += __shfl_down(v, off);
    if ((tid & 63) == 0) red[tid >> 6] = v;
    __syncthreads();
    if (tid == 0) {
        float s = 0.f;
#pragma unroll
        for (int q = 0; q < 8; q++) s += red[q];
        out[0] = -s / (float)B_;
    }
}

extern "C" void kernel_launch(void* const* d_in, const int* in_sizes, int n_in,
                              void* d_out, int out_size, void* d_ws, size_t ws_size,
                              hipStream_t stream) {
    const float* seq    = (const float*)d_in[0];
    const float* Wenc   = (const float*)d_in[1];
    const float* benc   = (const float*)d_in[2];
    const float* Wemit  = (const float*)d_in[3];
    const float* bemit  = (const float*)d_in[4];
    const float* startt = (const float*)d_in[5];
    const float* trans  = (const float*)d_in[6];
    const float* endt   = (const float*)d_in[7];
    const int*   lengths= (const int*)d_in[8];
    const int*   labels = (const int*)d_in[9];

    char* w = (char*)d_ws;
    unsigned short* expem  = (unsigned short*)w;            // B*T*16 bf16 = 4,194,304 B
    float*          G0     = (float*)(w + 4194304);         // NC*132 f32  = 1,081,344 B
    float*          numpart= (float*)(w + 5275648);         // 512 f32
    float*          dens   = (float*)(w + 5277696);         // 16 f32
    float*          wpack  = (float*)(w + 5277760);         // 32*48 f32
    unsigned short* Afrag  = (unsigned short*)(w + 5283904);// 8*64*8 us
    float*          eT     = (float*)(w + 5292096);         // 121 f32
    float* out = (float*)d_out;

    k_prep<<<1, 256, 0, stream>>>(Wenc, benc, Wemit, trans, wpack, Afrag, eT);
    k_em<<<512, 256, 0, stream>>>(seq, Afrag, wpack, bemit, trans, startt, endt,
                                  lengths, labels, expem, numpart);
    k_chunks<<<(NC + 19) / 20, 256, 0, stream>>>(eT, lengths, expem, G0);
    k_comb<<<B_, 512, 0, stream>>>(startt, endt, expem, G0, dens);
    k_final<<<1, 512, 0, stream>>>(numpart, dens, out);
}

// Round 5
// 61.758 us; speedup vs baseline: 1.5019x; 1.3714x over previous
//
#include <hip/hip_runtime.h>
#include <hip/hip_bf16.h>

#define B_   16
#define T_   8192
#define H_   256
#define C_   11
#define KCH  256            // chunks per batch
#define LCH  32             // steps per chunk (T_/KCH)
#define NC   (B_*KCH)       // total chunks

typedef __attribute__((ext_vector_type(8))) short short8;
typedef __attribute__((ext_vector_type(4))) float f32x4;

// round-to-nearest-even fp32 -> bf16 (bits in low 16)
__device__ __forceinline__ unsigned bf16rne(float x) {
    unsigned b = __float_as_uint(x);
    return (b + 0x7fffu + ((b >> 16) & 1u)) >> 16;
}

// ---------------------------------------------------------------------------
// K0: prep — pack enc weights per (kb,g) in fragment order, Wemit^T A-frags,
// and exp(trans). Fragment k-map: k = 4*g + (e&3) + 16*(e>>2)  (consistent
// between A and B by construction; C/D layout is the HW-verified one).
// ---------------------------------------------------------------------------
__global__ __launch_bounds__(256) void k_prep(
    const float* __restrict__ Wenc, const float* __restrict__ benc,
    const float* __restrict__ Wemit, const float* __restrict__ trans,
    float* __restrict__ wpack, unsigned short* __restrict__ Afrag,
    float* __restrict__ eT)
{
    int tid = threadIdx.x;
    // wpack[kbg][48]: 40 used = 8 h-slots x (w0..w3, benc)
    for (int idx = tid; idx < 32 * 40; idx += 256) {
        int kbg = idx / 40, r = idx - kbg * 40;
        int s = r / 5, q = r - s * 5;
        int kb = kbg >> 2, g = kbg & 3;
        int h = 32 * kb + 4 * g + (s & 3) + 16 * (s >> 2);
        wpack[kbg * 48 + r] = (q < 4) ? Wenc[q * H_ + h] : benc[h];
    }
    // Afrag[kb][lane][e] = bf16(Wemit[k][i]), i = lane&15 (0 pad for i>=11)
    for (int idx = tid; idx < 8 * 64 * 8; idx += 256) {
        int e = idx & 7, lane = (idx >> 3) & 63, kb = idx >> 9;
        int g = lane >> 4, i = lane & 15;
        int h = 32 * kb + 4 * g + (e & 3) + 16 * (e >> 2);
        float v = (i < C_) ? Wemit[h * C_ + i] : 0.f;
        Afrag[idx] = (unsigned short)bf16rne(v);
    }
    if (tid < 121) eT[tid] = __expf(trans[tid]);
}

// component j (compile-time) of the packed weight block
#define WF(j) (((j) & 3) == 0 ? Wq[(j) >> 2].x : ((j) & 3) == 1 ? Wq[(j) >> 2].y \
             : ((j) & 3) == 2 ? Wq[(j) >> 2].z : Wq[(j) >> 2].w)

// ---------------------------------------------------------------------------
// K1: MFMA encoder+emissions+numerator. Wave = 4 tiles x 16 rows.
// B-frag (hidden) computed in-register: lane covers row t=lane&15 at its
// fragment's h-indices. A-frag = Wemit^T. em^T tile lands in C with
// row=c=4*(lane>>4)+reg, col=t=lane&15 (m89-verified layout).
// ---------------------------------------------------------------------------
__global__ __launch_bounds__(256) void k_em(
    const float* __restrict__ seq, const unsigned short* __restrict__ Afrag,
    const float* __restrict__ wpack, const float* __restrict__ bemit,
    const float* __restrict__ trans, const float* __restrict__ startt,
    const float* __restrict__ endt, const int* __restrict__ lengths,
    const int* __restrict__ labels,
    unsigned short* __restrict__ expem, float* __restrict__ numpart)
{
    __shared__ float red[4];
    int tid = threadIdx.x;
    int wid = tid >> 6, lane = tid & 63;
    int g = lane >> 4, li = lane & 15;

    int b = blockIdx.x >> 5;                          // 32 blocks per batch
    int tb0 = (blockIdx.x & 31) * 256 + wid * 64;     // within-batch wave base
    size_t grow0 = (size_t)b * T_ + tb0;

    float4 xs[4];
#pragma unroll
    for (int tt = 0; tt < 4; tt++)
        xs[tt] = *(const float4*)(seq + (grow0 + tt * 16 + li) * 4);

    f32x4 acc[4];
#pragma unroll
    for (int tt = 0; tt < 4; tt++) acc[tt] = (f32x4){0.f, 0.f, 0.f, 0.f};

#pragma unroll 1
    for (int kb = 0; kb < 8; kb++) {
        const float4* wp4 = (const float4*)(wpack + ((kb << 2) | g) * 48);
        float4 Wq[10];
#pragma unroll
        for (int i = 0; i < 10; i++) Wq[i] = wp4[i];
        short8 afk = *(const short8*)(Afrag + (kb << 9) + (lane << 3));

#pragma unroll
        for (int tt = 0; tt < 4; tt++) {
            float4 x = xs[tt];
            float hv[8];
#pragma unroll
            for (int e = 0; e < 8; e++) {
                float h = fmaf(x.x, WF(5 * e + 0),
                          fmaf(x.y, WF(5 * e + 1),
                          fmaf(x.z, WF(5 * e + 2),
                          fmaf(x.w, WF(5 * e + 3), WF(5 * e + 4)))));
                hv[e] = fmaxf(h, 0.f);
            }
            unsigned u0, u1, u2, u3;
            asm("v_cvt_pk_bf16_f32 %0, %1, %2" : "=v"(u0) : "v"(hv[0]), "v"(hv[1]));
            asm("v_cvt_pk_bf16_f32 %0, %1, %2" : "=v"(u1) : "v"(hv[2]), "v"(hv[3]));
            asm("v_cvt_pk_bf16_f32 %0, %1, %2" : "=v"(u2) : "v"(hv[4]), "v"(hv[5]));
            asm("v_cvt_pk_bf16_f32 %0, %1, %2" : "=v"(u3) : "v"(hv[6]), "v"(hv[7]));
            union { short8 s8; uint4 u4; } bfu;
            bfu.u4 = make_uint4(u0, u1, u2, u3);
            acc[tt] = __builtin_amdgcn_mfma_f32_16x16x32_bf16(afk, bfu.s8, acc[tt], 0, 0, 0);
        }
    }

    // epilogue: +bemit, numerator gather (fp32 em), exp, bf16 pack, store
    int len = lengths[b];
    const int* lab = labels + (size_t)b * T_;
    float bm[4];
#pragma unroll
    for (int r = 0; r < 4; r++) {
        int c = 4 * g + r;
        bm[r] = (c < C_) ? bemit[c] : 0.f;
    }

    float nacc = 0.f;
#pragma unroll
    for (int tt = 0; tt < 4; tt++) {
        float em0 = acc[tt].x + bm[0];
        float em1 = acc[tt].y + bm[1];
        float em2 = acc[tt].z + bm[2];
        float em3 = acc[tt].w + bm[3];

        int t = tb0 + tt * 16 + li;
        int tg = lab[t]; tg = tg < 0 ? 0 : tg;
        if (g == (tg >> 2) && t < len) {
            int r = tg & 3;
            float emtg = r == 0 ? em0 : r == 1 ? em1 : r == 2 ? em2 : em3;
            float contrib;
            if (t == 0) {
                contrib = startt[tg] + emtg;
            } else {
                int tp = lab[t - 1]; tp = tp < 0 ? 0 : tp;
                contrib = trans[tp * C_ + tg] + emtg;
            }
            if (t == len - 1) contrib += endt[tg];
            nacc += contrib;
        }

        if (g < 3) {
            float e0 = __expf(em0), e1 = __expf(em1);
            float e2 = __expf(em2), e3 = __expf(em3);
            unsigned u0, u1;
            asm("v_cvt_pk_bf16_f32 %0, %1, %2" : "=v"(u0) : "v"(e0), "v"(e1));
            asm("v_cvt_pk_bf16_f32 %0, %1, %2" : "=v"(u1) : "v"(e2), "v"(e3));
            *(uint2*)(expem + (grow0 + tt * 16 + li) * 16 + g * 4) = make_uint2(u0, u1);
        }
    }

#pragma unroll
    for (int off = 32; off > 0; off >>= 1) nacc += __shfl_down(nacc, off);
    if (lane == 0) red[wid] = nacc;
    __syncthreads();
    if (tid == 0) numpart[blockIdx.x] = red[0] + red[1] + red[2] + red[3];
}

// ---------------------------------------------------------------------------
// bf16 emission row load/unpack helpers
// ---------------------------------------------------------------------------
__device__ __forceinline__ void loadRow(const unsigned short* __restrict__ p,
                                        uint4& qa, uint2& qb) {
    qa = *(const uint4*)p;
    qb = *(const uint2*)(p + 8);
}
__device__ __forceinline__ void unpackRow(uint4 qa, uint2 qb, float* emv) {
    emv[0]  = __uint_as_float(qa.x << 16);
    emv[1]  = __uint_as_float(qa.x & 0xffff0000u);
    emv[2]  = __uint_as_float(qa.y << 16);
    emv[3]  = __uint_as_float(qa.y & 0xffff0000u);
    emv[4]  = __uint_as_float(qa.z << 16);
    emv[5]  = __uint_as_float(qa.z & 0xffff0000u);
    emv[6]  = __uint_as_float(qa.w << 16);
    emv[7]  = __uint_as_float(qa.w & 0xffff0000u);
    emv[8]  = __uint_as_float(qb.x << 16);
    emv[9]  = __uint_as_float(qb.x & 0xffff0000u);
    emv[10] = __uint_as_float(qb.y << 16);
}

// ---------------------------------------------------------------------------
// K2: per-chunk transfer matrices, probability domain, per-row rescale.
// 1 wave/block, __launch_bounds__(64,1) -> up to 256 VGPR so eT[121] stays
// register-resident; asm "+v" pins prevent the compiler rematerializing the
// loads inside the matvec (the r4 failure mode: VGPR=36, SMEM-latency-bound).
// ---------------------------------------------------------------------------
__global__ __launch_bounds__(64, 1) void k_chunks(
    const float* __restrict__ eTg, const int* __restrict__ lengths,
    const unsigned short* __restrict__ expem, float* __restrict__ G)
{
    int lane = threadIdx.x;
    int ciw = lane / C_;            // 5 chunks per wave (55/64 lanes)
    int i = lane - ciw * C_;
    int cid = blockIdx.x * 5 + ciw;
    if (ciw >= 5 || cid >= NC) return;

    int b = cid >> 8;
    int k = cid & (KCH - 1);
    int t0 = 1 + k * LCH;
    int len = lengths[b];
    float* o = G + (size_t)cid * 132 + i * 12;

    if (t0 >= len) {                 // fully inactive -> identity
#pragma unroll
        for (int j = 0; j < C_; j++) o[j] = (j == i) ? 1.f : 0.f;
        o[11] = 0.f;
        return;
    }

    float eT[121];
#pragma unroll
    for (int z = 0; z < 121; z++) eT[z] = eTg[z];
#pragma unroll
    for (int z = 0; z < 121; z++) asm volatile("" : "+v"(eT[z]));  // pin in VGPR

    float g[C_];
#pragma unroll
    for (int j = 0; j < C_; j++) g[j] = (j == i) ? 1.f : 0.f;
    float ls = 0.f;

    const unsigned short* emb = expem + (size_t)b * T_ * 16;
    bool full = (t0 + LCH <= len);

    if (full) {
        uint4 ca; uint2 cb;
        loadRow(emb + (size_t)t0 * 16, ca, cb);
#pragma unroll 1
        for (int su = 0; su < LCH / 4; su++) {
#pragma unroll
            for (int ss = 0; ss < 4; ss++) {
                int t = t0 + su * 4 + ss;
                int tn = t + 1; tn = (tn < T_) ? tn : (T_ - 1);
                uint4 na; uint2 nb;
                loadRow(emb + (size_t)tn * 16, na, nb);   // prefetch next
                float emv[C_];
                unpackRow(ca, cb, emv);
                float nxt[C_];
#pragma unroll
                for (int j = 0; j < C_; j++) nxt[j] = g[0] * eT[j];
#pragma unroll
                for (int kk = 1; kk < C_; kk++)
#pragma unroll
                    for (int j = 0; j < C_; j++)
                        nxt[j] = fmaf(g[kk], eT[kk * C_ + j], nxt[j]);
#pragma unroll
                for (int j = 0; j < C_; j++) g[j] = nxt[j] * emv[j];
                ca = na; cb = nb;
            }
            float s = 0.f;
#pragma unroll
            for (int j = 0; j < C_; j++) s += g[j];
            float r = 1.f / s;
#pragma unroll
            for (int j = 0; j < C_; j++) g[j] *= r;
            ls += __logf(s);
        }
    } else {                          // boundary chunk (rare)
#pragma unroll 1
        for (int su = 0; su < LCH / 4; su++) {
#pragma unroll
            for (int ss = 0; ss < 4; ss++) {
                int t = t0 + su * 4 + ss;
                int tc = (t < T_) ? t : (T_ - 1);
                uint4 ca; uint2 cb;
                loadRow(emb + (size_t)tc * 16, ca, cb);
                float emv[C_];
                unpackRow(ca, cb, emv);
                float nxt[C_];
#pragma unroll
                for (int j = 0; j < C_; j++) nxt[j] = g[0] * eT[j];
#pragma unroll
                for (int kk = 1; kk < C_; kk++)
#pragma unroll
                    for (int j = 0; j < C_; j++)
                        nxt[j] = fmaf(g[kk], eT[kk * C_ + j], nxt[j]);
                bool act = (t < len);
#pragma unroll
                for (int j = 0; j < C_; j++) g[j] = act ? nxt[j] * emv[j] : g[j];
            }
            float s = 0.f;
#pragma unroll
            for (int j = 0; j < C_; j++) s += g[j];
            float r = 1.f / s;
#pragma unroll
            for (int j = 0; j < C_; j++) g[j] *= r;
            ls += __logf(s);
        }
    }

#pragma unroll
    for (int j = 0; j < C_; j++) o[j] = g[j];
    o[11] = ls;
}

// ---------------------------------------------------------------------------
// K3: per-batch tree combine entirely in LDS (135 KiB), 512 threads, then den.
// ---------------------------------------------------------------------------
__global__ __launch_bounds__(512, 1) void k_comb(
    const float* __restrict__ startt, const float* __restrict__ endt,
    const unsigned short* __restrict__ expem, const float* __restrict__ G0,
    float* __restrict__ dens)
{
    __shared__ float M[KCH * 132];     // 135168 bytes
    int b = blockIdx.x, tid = threadIdx.x;
    const float4* src = (const float4*)(G0 + (size_t)b * KCH * 132);
    float4* dst = (float4*)M;
#pragma unroll 2
    for (int idx = tid; idx < KCH * 132 / 4; idx += 512) dst[idx] = src[idx];
    __syncthreads();

    for (int stride = 1; stride < KCH; stride <<= 1) {
        int npair = KCH / (2 * stride);
        for (int task = tid; task < npair * C_; task += 512) {
            int p = task / C_, i = task - p * C_;
            float* A  = M + (size_t)(2 * stride * p) * 132;
            float* Bm = M + (size_t)(2 * stride * p + stride) * 132;
            float a[C_];
#pragma unroll
            for (int kk = 0; kk < C_; kk++) a[kk] = A[i * 12 + kk];
            float als = A[i * 12 + 11];
            float m = Bm[11];
#pragma unroll
            for (int kk = 1; kk < C_; kk++) m = fmaxf(m, Bm[kk * 12 + 11]);
            float wv[C_];
#pragma unroll
            for (int kk = 0; kk < C_; kk++)
                wv[kk] = a[kk] * __expf(Bm[kk * 12 + 11] - m);
            float out[C_];
#pragma unroll
            for (int j = 0; j < C_; j++) out[j] = wv[0] * Bm[j];
#pragma unroll
            for (int kk = 1; kk < C_; kk++)
#pragma unroll
                for (int j = 0; j < C_; j++)
                    out[j] = fmaf(wv[kk], Bm[kk * 12 + j], out[j]);
            float s = 0.f;
#pragma unroll
            for (int j = 0; j < C_; j++) s += out[j];
            float rr = 1.f / s;
#pragma unroll
            for (int j = 0; j < C_; j++) A[i * 12 + j] = out[j] * rr;
            A[i * 12 + 11] = als + m + __logf(s);
        }
        __syncthreads();
    }

    if (tid == 0) {
        const float* Cm = M;
        const unsigned short* em0 = expem + (size_t)b * T_ * 16;
        float av[C_];
        float mm = -1e30f;
#pragma unroll
        for (int i2 = 0; i2 < C_; i2++) {
            float e0 = __uint_as_float((unsigned)em0[i2] << 16);
            av[i2] = startt[i2] + __logf(e0) + Cm[i2 * 12 + 11];
            mm = fmaxf(mm, av[i2]);
        }
        float S[C_];
#pragma unroll
        for (int j = 0; j < C_; j++) S[j] = 0.f;
#pragma unroll
        for (int i2 = 0; i2 < C_; i2++) {
            float e = __expf(av[i2] - mm);
#pragma unroll
            for (int j = 0; j < C_; j++) S[j] = fmaf(e, Cm[i2 * 12 + j], S[j]);
        }
        float tot = 0.f;
#pragma unroll
        for (int j = 0; j < C_; j++) tot += S[j] * __expf(endt[j]);
        dens[b] = __logf(tot) + mm;
    }
}

// ---------------------------------------------------------------------------
// K4: final scalar: -(sum(numpart) - sum(dens)) / B
// ---------------------------------------------------------------------------
__global__ __launch_bounds__(512) void k_final(
    const float* __restrict__ numpart, const float* __restrict__ dens,
    float* __restrict__ out)
{
    __shared__ float red[8];
    int tid = threadIdx.x;
    float v = numpart[tid];
    if (tid < B_) v -= dens[tid];
#pragma unroll
    for (int off = 32; off > 0; off >>= 1) v += __shfl_down(v, off);
    if ((tid & 63) == 0) red[tid >> 6] = v;
    __syncthreads();
    if (tid == 0) {
        float s = 0.f;
#pragma unroll
        for (int q = 0; q < 8; q++) s += red[q];
        out[0] = -s / (float)B_;
    }
}

extern "C" void kernel_launch(void* const* d_in, const int* in_sizes, int n_in,
                              void* d_out, int out_size, void* d_ws, size_t ws_size,
                              hipStream_t stream) {
    const float* seq    = (const float*)d_in[0];
    const float* Wenc   = (const float*)d_in[1];
    const float* benc   = (const float*)d_in[2];
    const float* Wemit  = (const float*)d_in[3];
    const float* bemit  = (const float*)d_in[4];
    const float* startt = (const float*)d_in[5];
    const float* trans  = (const float*)d_in[6];
    const float* endt   = (const float*)d_in[7];
    const int*   lengths= (const int*)d_in[8];
    const int*   labels = (const int*)d_in[9];

    char* w = (char*)d_ws;
    unsigned short* expem  = (unsigned short*)w;            // B*T*16 bf16 = 4,194,304 B
    float*          G0     = (float*)(w + 4194304);         // NC*132 f32  = 1,081,344 B
    float*          numpart= (float*)(w + 5275648);         // 512 f32
    float*          dens   = (float*)(w + 5277696);         // 16 f32
    float*          wpack  = (float*)(w + 5277760);         // 32*48 f32
    unsigned short* Afrag  = (unsigned short*)(w + 5283904);// 8*64*8 us
    float*          eT     = (float*)(w + 5292096);         // 121 f32
    float* out = (float*)d_out;

    k_prep<<<1, 256, 0, stream>>>(Wenc, benc, Wemit, trans, wpack, Afrag, eT);
    k_em<<<512, 256, 0, stream>>>(seq, Afrag, wpack, bemit, trans, startt, endt,
                                  lengths, labels, expem, numpart);
    k_chunks<<<(NC + 4) / 5, 64, 0, stream>>>(eT, lengths, expem, G0);
    k_comb<<<B_, 512, 0, stream>>>(startt, endt, expem, G0, dens);
    k_final<<<1, 512, 0, stream>>>(numpart, dens, out);
}